// Round 7
// baseline (18.038 us; speedup 1.0000x reference)
//
#include <hip/hip_runtime.h>

// SpodNet: per-batch sequential column sweep (B=16384 independent 22x22 fp32).
// Output Theta never depends on W; per batch, for c = 0..21:
//   v' = Wcol @ (row c minus elem c); row/col c <- v' symmetrically.
// Round 7 (on top of round 6's 17.7us):
//  - row reads as 6 LDS instrs (b128x5 + b64, alignment-aware even/odd row)
//  - pipeline patch word (c+1,c) pulled via __shfl from its producer lane
//    (lane c&7, slot c>>3) instead of an LDS write->wait->read round trip
//  - NT cache hint (aux=2) on global_load_lds: input read exactly once,
//    keep L2 for the write-back stream. NT stores kept.

#define PP 22
#define PM 21
#define MAT 484                        // floats per matrix
#define TB 8                           // matrices per tile (one wave, 8 lanes each)
#define TILE_FLOATS (TB * MAT)         // 3872 floats = 15488 B

typedef const __attribute__((address_space(1))) void* gas_ptr;
typedef __attribute__((address_space(3))) void* las_ptr;
typedef float f32x4 __attribute__((ext_vector_type(4)));
typedef float f32x2 __attribute__((ext_vector_type(2)));

// Load row r (22 floats at byte offset r*88 from M, M 16B-aligned) into f[].
// r is a compile-time constant at every call site (full unroll) so the
// even/odd alignment split folds away.
__device__ __forceinline__ void load_row(const float* M, int r, float* f)
{
    const char* base = (const char*)M + r * 88;
    if ((r & 1) == 0) {                 // base 16B-aligned
        const f32x4* v4 = reinterpret_cast<const f32x4*>(base);
        #pragma unroll
        for (int h = 0; h < 5; ++h) {
            f32x4 t = v4[h];
            f[4 * h] = t.x; f[4 * h + 1] = t.y;
            f[4 * h + 2] = t.z; f[4 * h + 3] = t.w;
        }
        f32x2 t2 = *reinterpret_cast<const f32x2*>(base + 80);
        f[20] = t2.x; f[21] = t2.y;
    } else {                            // base+8 is 16B-aligned
        f32x2 t2 = *reinterpret_cast<const f32x2*>(base);
        f[0] = t2.x; f[1] = t2.y;
        const f32x4* v4 = reinterpret_cast<const f32x4*>(base + 8);
        #pragma unroll
        for (int h = 0; h < 5; ++h) {
            f32x4 t = v4[h];
            f[2 + 4 * h] = t.x; f[3 + 4 * h] = t.y;
            f[4 + 4 * h] = t.z; f[5 + 4 * h] = t.w;
        }
    }
}

__global__ __launch_bounds__(64)
void spodnet_sweep(const float* __restrict__ theta_in,
                   const float* __restrict__ wcol,
                   float* __restrict__ theta_out)
{
    __shared__ float lds[TILE_FLOATS];   // linear (glds destination), 16B-aligned
    const int lane = threadIdx.x;
    const int g = lane >> 3;             // matrix within tile
    const int k = lane & 7;              // lane within 8-lane group

    const float* gin  = theta_in  + (long)blockIdx.x * TILE_FLOATS;
    float*       gout = theta_out + (long)blockIdx.x * TILE_FLOATS;

    // ---- async stage: global -> LDS, 16 vm ops, NT hint ----
    {
        const char* src = (const char*)gin;
        #pragma unroll
        for (int it = 0; it < 15; ++it) {
            __builtin_amdgcn_global_load_lds(
                (gas_ptr)(src + it * 1024 + lane * 16),
                (las_ptr)((char*)lds + it * 1024), 16, 0, 2 /*nt*/);
        }
        if (lane < 8) {
            __builtin_amdgcn_global_load_lds(
                (gas_ptr)(src + 15360 + lane * 16),
                (las_ptr)((char*)lds + 15360), 16, 0, 2 /*nt*/);
        }
    }

    // ---- Wcol rows k, k+8, k+16 (clamped; k>=5 never uses the 3rd result) ----
    float w0[PM], w1[PM], w2[PM];
    {
        const int r0 = k, r1 = k + 8, r2 = (k < 5) ? (k + 16) : 20;
        #pragma unroll
        for (int j = 0; j < PM; ++j) {
            w0[j] = wcol[r0 * PM + j];
            w1[j] = wcol[r1 * PM + j];
            w2[j] = wcol[r2 * PM + j];
        }
    }

    asm volatile("s_waitcnt vmcnt(0)" ::: "memory");
    __builtin_amdgcn_sched_barrier(0);

    float* M = &lds[g * MAT];

    // ---- pipelined column sweep (fully unrolled, all indices static) ----
    float fb[2][PP];   // fb[c&1] = row c
    load_row(M, 0, fb[0]);

    #pragma unroll
    for (int c = 0; c < PP; ++c) {
        const int cur = c & 1, nxt = cur ^ 1;

        // early prefetch of row c+1: only word (c+1,c) is stale (patched
        // below from the producer lane's register via shfl)
        if (c < PP - 1)
            load_row(M, c + 1, fb[nxt]);

        // FMAs over j != c-1 (two partial chains), fresh term j = c-1 last
        float a0 = 0.f, a1 = 0.f, a2 = 0.f;
        float p0 = 0.f, p1 = 0.f, p2 = 0.f;
        int cnt = 0;
        #pragma unroll
        for (int j = 0; j < PM; ++j) {
            if (j == c - 1) continue;              // compile-time skip
            const int mj = j + (j >= c ? 1 : 0);   // compile-time
            const float fv = fb[cur][mj];
            if ((cnt & 1) == 0) {
                a0 = fmaf(w0[j], fv, a0);
                a1 = fmaf(w1[j], fv, a1);
                a2 = fmaf(w2[j], fv, a2);
            } else {
                p0 = fmaf(w0[j], fv, p0);
                p1 = fmaf(w1[j], fv, p1);
                p2 = fmaf(w2[j], fv, p2);
            }
            ++cnt;
        }
        a0 += p0; a1 += p1; a2 += p2;
        if (c >= 1) {                              // fresh value (c, c-1), mj = c-1
            const float fv = fb[cur][c - 1];
            a0 = fmaf(w0[c - 1], fv, a0);
            a1 = fmaf(w1[c - 1], fv, a1);
            a2 = fmaf(w2[c - 1], fv, a2);
        }

        // patch word (c+1, c): produced this column by lane (c&7), slot (c>>3).
        // (solve b + (b>=c) == c+1 -> b = c). Register pull, no LDS round trip.
        if (c < PP - 1) {
            const float pv = (c >> 3) == 0 ? a0 : ((c >> 3) == 1 ? a1 : a2);
            const int src = (lane & 56) | (c & 7);
            fb[nxt][c] = __shfl(pv, src, 64);
        }

        // column writes [mi, c]: re-read at step mi (as row-mi prefix), or final
        const int mi0 = k      + (k      >= c ? 1 : 0);
        const int mi1 = k + 8  + (k + 8  >= c ? 1 : 0);
        const int mi2 = k + 16 + (k + 16 >= c ? 1 : 0);
        M[mi0 * PP + c] = a0;
        M[mi1 * PP + c] = a1;
        if (k < 5) M[mi2 * PP + c] = a2;
        // row writes [c, mi]: only mi < c are final (mi > c are dead)
        if (mi0 < c) M[c * PP + mi0] = a0;
        if (mi1 < c) M[c * PP + mi1] = a1;
        if (k < 5 && mi2 < c) M[c * PP + mi2] = a2;
    }

    // ---- store: LDS -> global, nontemporal float4 ----
    {
        const f32x4* l4 = reinterpret_cast<const f32x4*>(lds);
        f32x4* g4 = reinterpret_cast<f32x4*>(gout);
        #pragma unroll
        for (int it = 0; it < 15; ++it)
            __builtin_nontemporal_store(l4[it * 64 + lane], &g4[it * 64 + lane]);
        if (lane < 8)
            __builtin_nontemporal_store(l4[960 + lane], &g4[960 + lane]);
    }
}

extern "C" void kernel_launch(void* const* d_in, const int* in_sizes, int n_in,
                              void* d_out, int out_size, void* d_ws, size_t ws_size,
                              hipStream_t stream) {
    const float* theta = (const float*)d_in[0];
    const float* wcol  = (const float*)d_in[1];
    float* out = (float*)d_out;

    const int Btot = in_sizes[0] / (PP * PP);   // 16384
    const int grid = Btot / TB;                 // 2048 blocks, 8 waves/CU
    hipLaunchKernelGGL(spodnet_sweep, dim3(grid), dim3(64), 0, stream,
                       theta, wcol, out);
}

// Round 8
// 17.695 us; speedup vs baseline: 1.0194x; 1.0194x over previous
//
#include <hip/hip_runtime.h>

// SpodNet: per-batch sequential column sweep (B=16384 independent 22x22 fp32).
// Output Theta never depends on W; per batch, for c = 0..21:
//   v' = Wcol @ (row c minus elem c); row/col c <- v' symmetrically.
// Round 8 = round 6 exactly (best measured: 17.73 us). Round 7's bundle
// (NT load hint, b128 row reads, shfl patch word) was null-to-negative and
// is reverted wholesale. Structure: 2048 blocks x 1 wave, 8 matrices/wave
// (8-lane groups), glds staging, vmcnt(0), software-pipelined column loop
// (prefetch row c+1 during column c's FMAs; patch word (c+1,c) via LDS),
// nontemporal float4 stores.

#define PP 22
#define PM 21
#define MAT 484                        // floats per matrix
#define TB 8                           // matrices per tile (one wave, 8 lanes each)
#define TILE_FLOATS (TB * MAT)         // 3872 floats = 15488 B

typedef const __attribute__((address_space(1))) void* gas_ptr;
typedef __attribute__((address_space(3))) void* las_ptr;
typedef float f32x4 __attribute__((ext_vector_type(4)));
typedef float f32x2 __attribute__((ext_vector_type(2)));

__global__ __launch_bounds__(64)
void spodnet_sweep(const float* __restrict__ theta_in,
                   const float* __restrict__ wcol,
                   float* __restrict__ theta_out)
{
    __shared__ float lds[TILE_FLOATS];   // linear (glds destination)
    const int lane = threadIdx.x;
    const int g = lane >> 3;             // matrix within tile
    const int k = lane & 7;              // lane within 8-lane group

    const float* gin  = theta_in  + (long)blockIdx.x * TILE_FLOATS;
    float*       gout = theta_out + (long)blockIdx.x * TILE_FLOATS;

    // ---- async stage: global -> LDS, 16 vm ops ----
    {
        const char* src = (const char*)gin;
        #pragma unroll
        for (int it = 0; it < 15; ++it) {
            __builtin_amdgcn_global_load_lds(
                (gas_ptr)(src + it * 1024 + lane * 16),
                (las_ptr)((char*)lds + it * 1024), 16, 0, 0);
        }
        if (lane < 8) {
            __builtin_amdgcn_global_load_lds(
                (gas_ptr)(src + 15360 + lane * 16),
                (las_ptr)((char*)lds + 15360), 16, 0, 0);
        }
    }

    // ---- Wcol rows k, k+8, k+16 (clamped; k>=5 never uses the 3rd result) ----
    float w0[PM], w1[PM], w2[PM];
    {
        const int r0 = k, r1 = k + 8, r2 = (k < 5) ? (k + 16) : 20;
        #pragma unroll
        for (int j = 0; j < PM; ++j) {
            w0[j] = wcol[r0 * PM + j];
            w1[j] = wcol[r1 * PM + j];
            w2[j] = wcol[r2 * PM + j];
        }
    }

    asm volatile("s_waitcnt vmcnt(0)" ::: "memory");
    __builtin_amdgcn_sched_barrier(0);

    float* M = &lds[g * MAT];

    // ---- pipelined column sweep (fully unrolled, all indices static) ----
    float fb[2][PP];   // fb[c&1] = row c
    {
        const f32x2* row = reinterpret_cast<const f32x2*>(&M[0]);
        #pragma unroll
        for (int h = 0; h < 11; ++h) {
            f32x2 t = row[h];
            fb[0][2 * h] = t.x; fb[0][2 * h + 1] = t.y;
        }
    }

    #pragma unroll
    for (int c = 0; c < PP; ++c) {
        const int cur = c & 1, nxt = cur ^ 1;

        // early prefetch of row c+1: only word (c+1,c) is stale (patched below)
        if (c < PP - 1) {
            const f32x2* row = reinterpret_cast<const f32x2*>(&M[(c + 1) * PP]);
            #pragma unroll
            for (int h = 0; h < 11; ++h) {
                f32x2 t = row[h];
                fb[nxt][2 * h] = t.x; fb[nxt][2 * h + 1] = t.y;
            }
        }

        // FMAs over j != c-1 (two partial chains), fresh term j = c-1 last
        float a0 = 0.f, a1 = 0.f, a2 = 0.f;
        float p0 = 0.f, p1 = 0.f, p2 = 0.f;
        int cnt = 0;
        #pragma unroll
        for (int j = 0; j < PM; ++j) {
            if (j == c - 1) continue;              // compile-time skip
            const int mj = j + (j >= c ? 1 : 0);   // compile-time
            const float fv = fb[cur][mj];
            if ((cnt & 1) == 0) {
                a0 = fmaf(w0[j], fv, a0);
                a1 = fmaf(w1[j], fv, a1);
                a2 = fmaf(w2[j], fv, a2);
            } else {
                p0 = fmaf(w0[j], fv, p0);
                p1 = fmaf(w1[j], fv, p1);
                p2 = fmaf(w2[j], fv, p2);
            }
            ++cnt;
        }
        a0 += p0; a1 += p1; a2 += p2;
        if (c >= 1) {                              // fresh value (c, c-1), mj = c-1
            const float fv = fb[cur][c - 1];
            a0 = fmaf(w0[c - 1], fv, a0);
            a1 = fmaf(w1[c - 1], fv, a1);
            a2 = fmaf(w2[c - 1], fv, a2);
        }

        // column writes [mi, c]: re-read at step mi, or final
        const int mi0 = k      + (k      >= c ? 1 : 0);
        const int mi1 = k + 8  + (k + 8  >= c ? 1 : 0);
        const int mi2 = k + 16 + (k + 16 >= c ? 1 : 0);
        M[mi0 * PP + c] = a0;
        M[mi1 * PP + c] = a1;
        if (k < 5) M[mi2 * PP + c] = a2;
        // row writes [c, mi]: only mi < c are final (mi > c are dead)
        if (mi0 < c) M[c * PP + mi0] = a0;
        if (mi1 < c) M[c * PP + mi1] = a1;
        if (k < 5 && mi2 < c) M[c * PP + mi2] = a2;

        // patch the one fresh word of row c+1: (c+1, c), just written above
        if (c < PP - 1)
            fb[nxt][c] = M[(c + 1) * PP + c];
    }

    // ---- store: LDS -> global, nontemporal float4 (native clang vector) ----
    {
        const f32x4* l4 = reinterpret_cast<const f32x4*>(lds);
        f32x4* g4 = reinterpret_cast<f32x4*>(gout);
        #pragma unroll
        for (int it = 0; it < 15; ++it)
            __builtin_nontemporal_store(l4[it * 64 + lane], &g4[it * 64 + lane]);
        if (lane < 8)
            __builtin_nontemporal_store(l4[960 + lane], &g4[960 + lane]);
    }
}

extern "C" void kernel_launch(void* const* d_in, const int* in_sizes, int n_in,
                              void* d_out, int out_size, void* d_ws, size_t ws_size,
                              hipStream_t stream) {
    const float* theta = (const float*)d_in[0];
    const float* wcol  = (const float*)d_in[1];
    float* out = (float*)d_out;

    const int Btot = in_sizes[0] / (PP * PP);   // 16384
    const int grid = Btot / TB;                 // 2048 blocks, 8 waves/CU
    hipLaunchKernelGGL(spodnet_sweep, dim3(grid), dim3(64), 0, stream,
                       theta, wcol, out);
}